// Round 1
// baseline (529.829 us; speedup 1.0000x reference)
//
#include <hip/hip_runtime.h>

typedef unsigned int u32;
typedef unsigned short u16;
typedef unsigned long long u64;

using f32x4 = __attribute__((ext_vector_type(4))) float;
using bf16x8 = __attribute__((ext_vector_type(8))) short;

#define BN_EPS 1e-5f

__device__ __forceinline__ float bflo(u32 u) {
    union { u32 u; float f; } v; v.u = u << 16; return v.f;
}
__device__ __forceinline__ float bfhi(u32 u) {
    union { u32 u; float f; } v; v.u = u & 0xffff0000u; return v.f;
}
__device__ __forceinline__ u32 f2bf(float f) {   // round-to-nearest-even bf16 bits
    union { float f; u32 u; } v; v.f = f;
    return (v.u + 0x7fffu + ((v.u >> 16) & 1u)) >> 16;
}

// ---------------- edge dtype detect + convert ----------------
__global__ void detect_k(const void* ei, int* flag, int nnode) {
    const u64* p = (const u64*)ei;
    int lane = threadIdx.x & 63;
    u64 v = p[lane];
    int ok = (v < (u64)nnode);
    int all64 = __all(ok);
    if (threadIdx.x == 0) *flag = all64 ? 1 : 0;
}

__global__ void convert_edges_k(const void* ei, int* __restrict__ src, int* __restrict__ dst,
                                const int* __restrict__ flag, int E) {
    int is64 = *flag;
    int i = blockIdx.x * blockDim.x + threadIdx.x;
    int stride = gridDim.x * blockDim.x;
    if (is64) {
        const long long* p = (const long long*)ei;
        for (; i < E; i += stride) { src[i] = (int)p[i]; dst[i] = (int)p[E + i]; }
    } else {
        const int* p = (const int*)ei;
        for (; i < E; i += stride) { src[i] = p[i]; dst[i] = p[E + i]; }
    }
}

// ---------------- degree / dinv ----------------
__global__ void deg_count_k(const int* __restrict__ dst, int* __restrict__ degi, int E) {
    int i = blockIdx.x * blockDim.x + threadIdx.x;
    int stride = gridDim.x * blockDim.x;
    for (; i < E; i += stride) atomicAdd(&degi[dst[i]], 1);
}

__global__ void dinv_k(const int* __restrict__ degi, float* __restrict__ dinv, int n) {
    int i = blockIdx.x * blockDim.x + threadIdx.x;
    int stride = gridDim.x * blockDim.x;
    for (; i < n; i += stride) dinv[i] = rsqrtf((float)(degi[i] + 1)); // +1 self-loop
}

// ---------------- hierarchical exclusive scan (row_ptr) ----------------
__global__ void block_sum_k(const int* __restrict__ counts, int* __restrict__ bsum, int n) {
    __shared__ int red[4];
    int idx = blockIdx.x * 256 + threadIdx.x;
    int v = (idx < n) ? counts[idx] : 0;
#pragma unroll
    for (int m = 32; m >= 1; m >>= 1) v += __shfl_xor(v, m);
    int lane = threadIdx.x & 63, w = threadIdx.x >> 6;
    if (lane == 0) red[w] = v;
    __syncthreads();
    if (threadIdx.x == 0) bsum[blockIdx.x] = red[0] + red[1] + red[2] + red[3];
}

__global__ void scan_bsum_k(int* bsum, int nb) { // 1 block, 256 thr, nb<=256
    __shared__ int sd[256];
    int t = threadIdx.x;
    int v = (t < nb) ? bsum[t] : 0;
    sd[t] = v; __syncthreads();
    for (int off = 1; off < 256; off <<= 1) {
        int u = (t >= off) ? sd[t - off] : 0;
        __syncthreads();
        sd[t] += u;
        __syncthreads();
    }
    if (t < nb) bsum[t] = sd[t] - v; // exclusive
}

__global__ void block_scan_k(const int* __restrict__ counts, const int* __restrict__ bsum,
                             int* __restrict__ rp, int n) {
    __shared__ int sd[256];
    int t = threadIdx.x;
    int idx = blockIdx.x * 256 + t;
    int v = (idx < n) ? counts[idx] : 0;
    sd[t] = v; __syncthreads();
    for (int off = 1; off < 256; off <<= 1) {
        int u = (t >= off) ? sd[t - off] : 0;
        __syncthreads();
        sd[t] += u;
        __syncthreads();
    }
    if (idx < n) rp[idx + 1] = bsum[blockIdx.x] + sd[t];
    if (blockIdx.x == 0 && t == 0) rp[0] = 0;
}

__global__ void csr_fill_k(const int* __restrict__ src, const int* __restrict__ dst,
                           const int* __restrict__ rp, int* __restrict__ fill,
                           int* __restrict__ cs, int E) {
    int i = blockIdx.x * blockDim.x + threadIdx.x;
    int stride = gridDim.x * blockDim.x;
    for (; i < E; i += stride) {
        int d = dst[i];
        int pos = atomicAdd(&fill[d], 1);
        cs[rp[d] + pos] = src[i];
    }
}

// ---------------- conversions ----------------
__global__ void f32_to_bf16_k(const float* __restrict__ in, u16* __restrict__ out, int nquads) {
    int i = blockIdx.x * blockDim.x + threadIdx.x;
    int stride = gridDim.x * blockDim.x;
    for (; i < nquads; i += stride) {
        float4 v = ((const float4*)in)[i];
        u32 lo = f2bf(v.x) | (f2bf(v.y) << 16);
        u32 hi = f2bf(v.z) | (f2bf(v.w) << 16);
        ((uint2*)out)[i] = make_uint2(lo, hi);
    }
}

__global__ void transpose_w_k(const float* __restrict__ W, u16* __restrict__ Wt,
                              int din, int dout) {
    int i = blockIdx.x * blockDim.x + threadIdx.x;
    int total = din * dout;
    if (i < total) {
        int r = i / dout, c = i % dout;
        Wt[(size_t)c * din + r] = (u16)f2bf(W[i]);
    }
}

// ---------------- GCN aggregation: out[v] = dinv[v]*(sum_e dinv[src]*h[src]) + dinv[v]^2*h[v]
template <int DIN>
__global__ __launch_bounds__(256) void aggregate_k(
    const u16* __restrict__ H, u16* __restrict__ O,
    const float* __restrict__ dinv, const int* __restrict__ rp,
    const int* __restrict__ cs, int n)
{
    constexpr int U = DIN / 128; // u32 words per lane (1 or 2)
    int node = blockIdx.x * 4 + (threadIdx.x >> 6);
    if (node >= n) return;
    int lane = threadIdx.x & 63;
    const u32* Hu = (const u32*)H;
    float dv = dinv[node];
    float acc[2 * U];
    {
        const u32* row = Hu + (size_t)node * (DIN / 2);
#pragma unroll
        for (int j = 0; j < U; ++j) {
            u32 w = row[lane * U + j];
            acc[2 * j]     = dv * bflo(w);
            acc[2 * j + 1] = dv * bfhi(w);
        }
    }
    int e0 = rp[node], e1 = rp[node + 1];
    for (int e = e0; e < e1; ++e) {
        int s = cs[e];
        float w = dinv[s];
        const u32* row = Hu + (size_t)s * (DIN / 2);
#pragma unroll
        for (int j = 0; j < U; ++j) {
            u32 xx = row[lane * U + j];
            acc[2 * j]     = fmaf(w, bflo(xx), acc[2 * j]);
            acc[2 * j + 1] = fmaf(w, bfhi(xx), acc[2 * j + 1]);
        }
    }
    u32* orow = (u32*)O + (size_t)node * (DIN / 2);
#pragma unroll
    for (int j = 0; j < U; ++j) {
        float x0 = acc[2 * j] * dv, x1 = acc[2 * j + 1] * dv;
        orow[lane * U + j] = f2bf(x0) | (f2bf(x1) << 16);
    }
}

// ---------------- bf16 MFMA GEMM: out[M][256] = A[M][K] * Bt[256][K]^T + bias, fused colsum/colsumsq
template <int K>
__global__ __launch_bounds__(256) void gemm_bf16(
    const u16* __restrict__ A, const u16* __restrict__ Bt,
    const float* __restrict__ bias, float* __restrict__ out,
    float* __restrict__ colacc, int M)
{
    // LDS layout [k_hi=4][dim=128][k_lo=8] bf16 — conflict-free ds_read_b128,
    // linear-compatible with global_load_lds (chunk c: dim=c&127, k_hi=c>>7)
    __shared__ __align__(16) u16 lA[4096];
    __shared__ __align__(16) u16 lB[4096];
    const int tid = threadIdx.x;
    const int lane = tid & 63;
    const int wid = tid >> 6;
    const int wm = wid >> 1, wn = wid & 1;
    const int l15 = lane & 15, khi = lane >> 4;
    const int row0 = blockIdx.x * 128;
    const int col0 = blockIdx.y * 128;

    f32x4 acc[4][4];
#pragma unroll
    for (int i = 0; i < 4; ++i)
#pragma unroll
        for (int j = 0; j < 4; ++j)
            acc[i][j] = (f32x4){0.f, 0.f, 0.f, 0.f};

    for (int k0 = 0; k0 < K; k0 += 32) {
#pragma unroll
        for (int t = 0; t < 2; ++t) {
            int c = t * 256 + wid * 64 + lane;
            int r = c & 127, kh = c >> 7;
            int ar = row0 + r; if (ar > M - 1) ar = M - 1;
            const u16* ga = A + (size_t)ar * K + k0 + kh * 8;
            u16* la = &lA[(t * 256 + wid * 64) * 8];
            __builtin_amdgcn_global_load_lds(
                (const __attribute__((address_space(1))) void*)ga,
                (__attribute__((address_space(3))) void*)la, 16, 0, 0);
            const u16* gb = Bt + (size_t)(col0 + r) * K + k0 + kh * 8;
            u16* lb = &lB[(t * 256 + wid * 64) * 8];
            __builtin_amdgcn_global_load_lds(
                (const __attribute__((address_space(1))) void*)gb,
                (__attribute__((address_space(3))) void*)lb, 16, 0, 0);
        }
        __syncthreads();
        bf16x8 afr[4], bfr[4];
#pragma unroll
        for (int mi = 0; mi < 4; ++mi)
            afr[mi] = *(const bf16x8*)&lA[khi * 1024 + (wm * 64 + mi * 16 + l15) * 8];
#pragma unroll
        for (int nj = 0; nj < 4; ++nj)
            bfr[nj] = *(const bf16x8*)&lB[khi * 1024 + (wn * 64 + nj * 16 + l15) * 8];
#pragma unroll
        for (int mi = 0; mi < 4; ++mi)
#pragma unroll
            for (int nj = 0; nj < 4; ++nj)
                acc[mi][nj] = __builtin_amdgcn_mfma_f32_16x16x32_bf16(
                    afr[mi], bfr[nj], acc[mi][nj], 0, 0, 0);
        __syncthreads();
    }

#pragma unroll
    for (int mi = 0; mi < 4; ++mi) {
#pragma unroll
        for (int nj = 0; nj < 4; ++nj) {
            int colg = col0 + wn * 64 + nj * 16 + l15;
            float bsv = bias[colg];
            float s = 0.f, q = 0.f;
#pragma unroll
            for (int i = 0; i < 4; ++i) {
                int rowg = row0 + wm * 64 + mi * 16 + khi * 4 + i;
                if (rowg < M) {
                    float v = acc[mi][nj][i] + bsv;
                    out[(size_t)rowg * 256 + colg] = v;
                    s += v; q += v * v;
                }
            }
            s += __shfl_xor(s, 16); s += __shfl_xor(s, 32);
            q += __shfl_xor(q, 16); q += __shfl_xor(q, 32);
            if (lane < 16) {
                atomicAdd(&colacc[colg], s);
                atomicAdd(&colacc[256 + colg], q);
            }
        }
    }
}

// ---------------- BN stats + apply ----------------
__global__ void bn_stats_k(const float* __restrict__ colacc, const float* __restrict__ gamma,
                           const float* __restrict__ beta, float* __restrict__ ss, int M) {
    int c = threadIdx.x; // 256
    float mean = colacc[c] / (float)M;
    float var = colacc[256 + c] / (float)M - mean * mean;
    var = fmaxf(var, 0.f);
    float sc = gamma[c] * rsqrtf(var + BN_EPS);
    ss[c] = sc;
    ss[256 + c] = beta[c] - mean * sc;
}

template <int MODE> // 0: write f32 (in-place ok); 1: write bf16
__global__ void bn_prelu_k(const float* __restrict__ in, float* __restrict__ outf,
                           u16* __restrict__ outh, const float* __restrict__ ss,
                           const float* __restrict__ aptr, int nquads) {
    float a = aptr[0];
    int i = blockIdx.x * blockDim.x + threadIdx.x;
    int stride = gridDim.x * blockDim.x;
    for (; i < nquads; i += stride) {
        float4 v = ((const float4*)in)[i];
        int c0 = (i * 4) & 255;
        float r0 = v.x * ss[c0 + 0] + ss[256 + c0 + 0];
        float r1 = v.y * ss[c0 + 1] + ss[256 + c0 + 1];
        float r2 = v.z * ss[c0 + 2] + ss[256 + c0 + 2];
        float r3 = v.w * ss[c0 + 3] + ss[256 + c0 + 3];
        r0 = r0 > 0.f ? r0 : a * r0;
        r1 = r1 > 0.f ? r1 : a * r1;
        r2 = r2 > 0.f ? r2 : a * r2;
        r3 = r3 > 0.f ? r3 : a * r3;
        if (MODE == 0) {
            ((float4*)outf)[i] = make_float4(r0, r1, r2, r3);
        } else {
            u32 lo = f2bf(r0) | (f2bf(r1) << 16);
            u32 hi = f2bf(r2) | (f2bf(r3) << 16);
            ((uint2*)outh)[i] = make_uint2(lo, hi);
        }
    }
}

extern "C" void kernel_launch(void* const* d_in, const int* in_sizes, int n_in,
                              void* d_out, int out_size, void* d_ws, size_t ws_size,
                              hipStream_t stream) {
    const float* x   = (const float*)d_in[0];
    const void*  ei  = d_in[1];
    const float* W0  = (const float*)d_in[2];
    const float* b0  = (const float*)d_in[3];
    const float* g0  = (const float*)d_in[4];
    const float* be0 = (const float*)d_in[5];
    const float* a0  = (const float*)d_in[6];
    const float* W1  = (const float*)d_in[7];
    const float* b1  = (const float*)d_in[8];
    const float* g1  = (const float*)d_in[9];
    const float* be1 = (const float*)d_in[10];
    const float* a1  = (const float*)d_in[11];
    float* out = (float*)d_out;

    const int n = in_sizes[0] / 128;
    const int E = in_sizes[1] / 2;

    char* ws = (char*)d_ws;
    size_t off = 0;
    auto alloc = [&](size_t bytes) {
        size_t r = off; off += (bytes + 255) & ~(size_t)255; return r;
    };
    size_t o_src  = alloc((size_t)E * 4);
    size_t o_dst  = alloc((size_t)E * 4);
    size_t o_deg  = alloc((size_t)n * 4);
    size_t o_fill = alloc((size_t)n * 4);
    size_t o_rp   = alloc((size_t)(n + 1) * 4);
    size_t o_bsum = alloc(4096);
    size_t o_flag = alloc(256);
    size_t o_dinv = alloc((size_t)n * 4);
    size_t o_csr  = alloc((size_t)E * 4);
    size_t o_col  = alloc(2048);
    size_t o_ss   = alloc(2048);
    size_t o_wt0  = alloc(256 * 128 * 2);
    size_t o_wt1  = alloc(256 * 256 * 2);
    size_t o_xh   = alloc((size_t)n * 128 * 2);
    size_t o_agg0 = alloc((size_t)n * 128 * 2);
    size_t o_y0   = alloc((size_t)n * 256 * 2);
    size_t o_agg1 = o_xh; // overlay: xh+agg0 are dead by the time agg1 is written

    int*   src32 = (int*)(ws + o_src);
    int*   dst32 = (int*)(ws + o_dst);
    int*   degi  = (int*)(ws + o_deg);
    int*   fill  = (int*)(ws + o_fill);
    int*   rp    = (int*)(ws + o_rp);
    int*   bsum  = (int*)(ws + o_bsum);
    int*   flag  = (int*)(ws + o_flag);
    float* dinv  = (float*)(ws + o_dinv);
    int*   csr   = (int*)(ws + o_csr);
    float* colac = (float*)(ws + o_col);
    float* ssbuf = (float*)(ws + o_ss);
    u16*   wt0   = (u16*)(ws + o_wt0);
    u16*   wt1   = (u16*)(ws + o_wt1);
    u16*   xh    = (u16*)(ws + o_xh);
    u16*   agg0  = (u16*)(ws + o_agg0);
    u16*   y0    = (u16*)(ws + o_y0);
    u16*   agg1  = (u16*)(ws + o_agg1);

    hipMemsetAsync(ws + o_deg, 0, (size_t)n * 4, stream);
    hipMemsetAsync(ws + o_fill, 0, (size_t)n * 4, stream);

    const int gE = (E + 255) / 256 < 4096 ? (E + 255) / 256 : 4096;
    const int gN = (n + 255) / 256; // 196 for n=50000 (fits single-block scan of bsum)

    detect_k<<<1, 64, 0, stream>>>(ei, flag, n);
    convert_edges_k<<<gE, 256, 0, stream>>>(ei, src32, dst32, flag, E);
    deg_count_k<<<gE, 256, 0, stream>>>(dst32, degi, E);
    dinv_k<<<gN, 256, 0, stream>>>(degi, dinv, n);
    block_sum_k<<<gN, 256, 0, stream>>>(degi, bsum, n);
    scan_bsum_k<<<1, 256, 0, stream>>>(bsum, gN);
    block_scan_k<<<gN, 256, 0, stream>>>(degi, bsum, rp, n);
    csr_fill_k<<<gE, 256, 0, stream>>>(src32, dst32, rp, fill, csr, E);

    f32_to_bf16_k<<<4096, 256, 0, stream>>>(x, xh, n * 128 / 4);
    transpose_w_k<<<(128 * 256 + 255) / 256, 256, 0, stream>>>(W0, wt0, 128, 256);
    transpose_w_k<<<(256 * 256 + 255) / 256, 256, 0, stream>>>(W1, wt1, 256, 256);

    const dim3 ggrid((n + 127) / 128, 2);

    // ---- layer 0 ----
    aggregate_k<128><<<(n + 3) / 4, 256, 0, stream>>>(xh, agg0, dinv, rp, csr, n);
    hipMemsetAsync(ws + o_col, 0, 2048, stream);
    gemm_bf16<128><<<ggrid, 256, 0, stream>>>(agg0, wt0, b0, out, colac, n);
    bn_stats_k<<<1, 256, 0, stream>>>(colac, g0, be0, ssbuf, n);
    bn_prelu_k<1><<<4096, 256, 0, stream>>>(out, nullptr, y0, ssbuf, a0, n * 256 / 4);

    // ---- layer 1 ----
    aggregate_k<256><<<(n + 3) / 4, 256, 0, stream>>>(y0, agg1, dinv, rp, csr, n);
    hipMemsetAsync(ws + o_col, 0, 2048, stream);
    gemm_bf16<256><<<ggrid, 256, 0, stream>>>(agg1, wt1, b1, out, colac, n);
    bn_stats_k<<<1, 256, 0, stream>>>(colac, g1, be1, ssbuf, n);
    bn_prelu_k<0><<<4096, 256, 0, stream>>>(out, out, nullptr, ssbuf, a1, n * 256 / 4);
}